// Round 2
// baseline (864.549 us; speedup 1.0000x reference)
//
#include <hip/hip_runtime.h>
#include <hip/hip_bf16.h>
#include <stdint.h>

#define M_DIM 8192
#define N_DIM 4096
#define K_DIM 4096

typedef __attribute__((ext_vector_type(8))) short short8;   // 8 bf16 = 4 VGPR
typedef __attribute__((ext_vector_type(4))) float f32x4;

__device__ __forceinline__ unsigned short f2bf(float f) {   // RNE f32->bf16
  unsigned int u = __float_as_uint(f);
  u += 0x7FFFu + ((u >> 16) & 1u);
  return (unsigned short)(u >> 16);
}
__device__ __forceinline__ float bf2f(unsigned short h) {
  return __uint_as_float(((unsigned int)h) << 16);
}

// ---------------- preprocessing ----------------
// Both preprocess kernels write PRE-SWIZZLED rows: within each aligned group
// of 4x 16B blocks (= one BK=32 K-step), block w goes to w ^ ((row>>1)&3).
// The GEMM stages these linearly via global_load_lds and applies the same XOR
// on the ds_read side (involution), giving ~2-way (free) LDS bank access.

__global__ __launch_bounds__(256) void binarize_w(const float* __restrict__ W,
                                                  unsigned short* __restrict__ Wb) {
  int gid = blockIdx.x * 256 + threadIdx.x;   // one thread per 8 elements
  int m  = gid >> 9;                          // 512 vec8 per row (K=4096)
  int b8 = gid & 511;
  const float4* src = (const float4*)(W + ((size_t)m << 12) + (b8 << 3));
  float4 x0 = src[0];
  float4 x1 = src[1];
  float v[8] = {x0.x, x0.y, x0.z, x0.w, x1.x, x1.y, x1.z, x1.w};
  short8 out;
#pragma unroll
  for (int i = 0; i < 8; ++i) {
    float f = v[i];
    out[i] = (short)(unsigned short)(f > 0.f ? 0x3F80u : (f < 0.f ? 0xBF80u : 0u));
  }
  int dstb = (b8 & ~3) | ((b8 & 3) ^ ((m >> 1) & 3));
  *(short8*)(Wb + ((size_t)m << 12) + (dstb << 3)) = out;
}

__global__ __launch_bounds__(256) void split_x(const float* __restrict__ X,
                                               unsigned short* __restrict__ Xhi,
                                               unsigned short* __restrict__ Xlo) {
  int gid = blockIdx.x * 256 + threadIdx.x;
  int m  = gid >> 9;
  int b8 = gid & 511;
  const float4* src = (const float4*)(X + ((size_t)m << 12) + (b8 << 3));
  float4 x0 = src[0];
  float4 x1 = src[1];
  float v[8] = {x0.x, x0.y, x0.z, x0.w, x1.x, x1.y, x1.z, x1.w};
  short8 hi, lo;
#pragma unroll
  for (int i = 0; i < 8; ++i) {
    unsigned short h = f2bf(v[i]);
    hi[i] = (short)h;
    lo[i] = (short)f2bf(v[i] - bf2f(h));
  }
  int dstb = (b8 & ~3) | ((b8 & 3) ^ ((m >> 1) & 3));
  size_t off = ((size_t)m << 12) + (dstb << 3);
  *(short8*)(Xhi + off) = hi;
  *(short8*)(Xlo + off) = lo;
}

// ---------------- GEMM: C[m][n] = sum_k (hi+lo)[m][k] * sign[n][k] + bias[n] ----------------
// m97 structure: 128x128 tile, BK=32, 4 waves (each owns a 64x64 quadrant,
// 4x4 grid of 16x16x32 MFMA). 3 LDS tiles (A_hi, A_lo, B_sign) staged with
// width-16 global_load_lds; B fragments reused across the hi/lo MFMA pair.

#define GLL(g, l)                                                         \
  __builtin_amdgcn_global_load_lds(                                       \
      (__attribute__((address_space(1))) void*)(g),                       \
      (__attribute__((address_space(3))) void*)(l), 16, 0, 0)

__global__ __launch_bounds__(256) void gemm_bin(const unsigned short* __restrict__ Xhi,
                                                const unsigned short* __restrict__ Xlo,
                                                const unsigned short* __restrict__ Wb,
                                                const float* __restrict__ bias,
                                                float* __restrict__ C) {
  __shared__ unsigned short As_hi[128 * 32];
  __shared__ unsigned short As_lo[128 * 32];
  __shared__ unsigned short Bs[128 * 32];

  const int NT_N = N_DIM / 128;                 // 32
  const int nwg = (M_DIM / 128) * NT_N;         // 2048 (% 8 == 0 -> bijective)
  int bid = blockIdx.x;
  int swz = (bid & 7) * (nwg >> 3) + (bid >> 3);  // XCD-aware swizzle
  int tm = swz / NT_N;
  int tn = swz % NT_N;

  int t = threadIdx.x;
  int lane = t & 63;
  int w = t >> 6;
  int wr = w >> 1;       // wave row (0..1) -> 64-row half
  int wc = w & 1;        // wave col (0..1) -> 64-col half

  // staging geometry: thread t covers row t>>2, 16B-block t&3 (64 rows/call)
  int srow = t >> 2;
  int sblk = t & 3;
  const unsigned short* gA_hi = Xhi + (size_t)(tm * 128 + srow) * K_DIM + sblk * 8;
  const unsigned short* gA_lo = Xlo + (size_t)(tm * 128 + srow) * K_DIM + sblk * 8;
  const unsigned short* gB   = Wb  + (size_t)(tn * 128 + srow) * K_DIM + sblk * 8;
  unsigned short* lA_hi = &As_hi[t * 8];
  unsigned short* lA_lo = &As_lo[t * 8];
  unsigned short* lB    = &Bs[t * 8];

  f32x4 acc[4][4];
#pragma unroll
  for (int i = 0; i < 4; ++i)
#pragma unroll
    for (int j = 0; j < 4; ++j) acc[i][j] = (f32x4){0.f, 0.f, 0.f, 0.f};

  // fragment LDS indices (constant over K-loop); XOR matches preprocessing
  int laddrA[4], laddrB[4];
  int kb = lane >> 4;
#pragma unroll
  for (int mi = 0; mi < 4; ++mi) {
    int lr = wr * 64 + mi * 16 + (lane & 15);
    laddrA[mi] = lr * 32 + (kb ^ ((lr >> 1) & 3)) * 8;
  }
#pragma unroll
  for (int ni = 0; ni < 4; ++ni) {
    int lc = wc * 64 + ni * 16 + (lane & 15);
    laddrB[ni] = lc * 32 + (kb ^ ((lc >> 1) & 3)) * 8;
  }

  for (int kt = 0; kt < K_DIM / 32; ++kt) {
    int c0 = kt * 32;  // shorts
    GLL(gA_hi + c0,                lA_hi);
    GLL(gA_hi + c0 + 64 * K_DIM,   lA_hi + 64 * 32);
    GLL(gA_lo + c0,                lA_lo);
    GLL(gA_lo + c0 + 64 * K_DIM,   lA_lo + 64 * 32);
    GLL(gB + c0,                   lB);
    GLL(gB + c0 + 64 * K_DIM,      lB + 64 * 32);
    __syncthreads();   // compiler emits vmcnt(0) drain here (m97 structure)

    short8 af[4], al[4], bf[4];
#pragma unroll
    for (int mi = 0; mi < 4; ++mi) af[mi] = *(const short8*)&As_hi[laddrA[mi]];
#pragma unroll
    for (int mi = 0; mi < 4; ++mi) al[mi] = *(const short8*)&As_lo[laddrA[mi]];
#pragma unroll
    for (int ni = 0; ni < 4; ++ni) bf[ni] = *(const short8*)&Bs[laddrB[ni]];

#pragma unroll
    for (int mi = 0; mi < 4; ++mi)
#pragma unroll
      for (int ni = 0; ni < 4; ++ni) {
        acc[mi][ni] = __builtin_amdgcn_mfma_f32_16x16x32_bf16(af[mi], bf[ni], acc[mi][ni], 0, 0, 0);
        acc[mi][ni] = __builtin_amdgcn_mfma_f32_16x16x32_bf16(al[mi], bf[ni], acc[mi][ni], 0, 0, 0);
      }
    __syncthreads();
  }

  // epilogue: C/D layout col=lane&15, row=(lane>>4)*4+j  [measured m89]
  int r0 = tm * 128 + wr * 64;
  int c0n = tn * 128 + wc * 64;
#pragma unroll
  for (int ni = 0; ni < 4; ++ni) {
    int col = c0n + ni * 16 + (lane & 15);
    float bv = bias[col];
#pragma unroll
    for (int mi = 0; mi < 4; ++mi) {
      int row = r0 + mi * 16 + ((lane >> 4) << 2);
#pragma unroll
      for (int j = 0; j < 4; ++j)
        C[(size_t)(row + j) * N_DIM + col] = acc[mi][ni][j] + bv;
    }
  }
}

// ---------------- correct-but-slow fallback (only if ws too small) ----------------
__global__ __launch_bounds__(256) void fallback_gemm(const float* __restrict__ X,
                                                     const float* __restrict__ W,
                                                     const float* __restrict__ bias,
                                                     float* __restrict__ C) {
  int n = blockIdx.x * 16 + (threadIdx.x & 15);
  int m = blockIdx.y * 16 + (threadIdx.x >> 4);
  const float* xr = X + (size_t)m * K_DIM;
  const float* wr = W + (size_t)n * K_DIM;
  float s = 0.f;
  for (int k = 0; k < K_DIM; k += 4) {
    float4 xv = *(const float4*)(xr + k);
    float4 wv = *(const float4*)(wr + k);
    s += xv.x * (wv.x > 0.f ? 1.f : (wv.x < 0.f ? -1.f : 0.f));
    s += xv.y * (wv.y > 0.f ? 1.f : (wv.y < 0.f ? -1.f : 0.f));
    s += xv.z * (wv.z > 0.f ? 1.f : (wv.z < 0.f ? -1.f : 0.f));
    s += xv.w * (wv.w > 0.f ? 1.f : (wv.w < 0.f ? -1.f : 0.f));
  }
  C[(size_t)m * N_DIM + n] = s + bias[n];
}

extern "C" void kernel_launch(void* const* d_in, const int* in_sizes, int n_in,
                              void* d_out, int out_size, void* d_ws, size_t ws_size,
                              hipStream_t stream) {
  const float* X    = (const float*)d_in[0];   // [4,2048,4096] f32
  const float* W    = (const float*)d_in[1];   // [4096,4096] f32
  const float* bias = (const float*)d_in[2];   // [4096] f32
  float* C = (float*)d_out;

  const size_t need = (size_t)N_DIM * K_DIM * 2          // Wb  (32 MB)
                    + 2 * (size_t)M_DIM * K_DIM * 2;     // Xhi+Xlo (128 MB)
  if (ws_size >= need) {
    unsigned short* Wb  = (unsigned short*)d_ws;
    unsigned short* Xhi = Wb + (size_t)N_DIM * K_DIM;
    unsigned short* Xlo = Xhi + (size_t)M_DIM * K_DIM;
    binarize_w<<<dim3((N_DIM * K_DIM) / 8 / 256), dim3(256), 0, stream>>>(W, Wb);
    split_x<<<dim3((M_DIM * K_DIM) / 8 / 256), dim3(256), 0, stream>>>(X, Xhi, Xlo);
    gemm_bin<<<dim3((M_DIM / 128) * (N_DIM / 128)), dim3(256), 0, stream>>>(Xhi, Xlo, Wb, bias, C);
  } else {
    fallback_gemm<<<dim3(N_DIM / 16, M_DIM / 16), dim3(256), 0, stream>>>(X, W, bias, C);
  }
}

// Round 3
// 644.667 us; speedup vs baseline: 1.3411x; 1.3411x over previous
//
#include <hip/hip_runtime.h>
#include <hip/hip_bf16.h>
#include <stdint.h>

#define M_DIM 8192
#define N_DIM 4096
#define K_DIM 4096

typedef __attribute__((ext_vector_type(8))) short short8;   // 8 bf16 = 4 VGPR
typedef __attribute__((ext_vector_type(4))) float f32x4;

__device__ __forceinline__ unsigned short f2bf(float f) {   // RNE f32->bf16
  unsigned int u = __float_as_uint(f);
  u += 0x7FFFu + ((u >> 16) & 1u);
  return (unsigned short)(u >> 16);
}
__device__ __forceinline__ float bf2f(unsigned short h) {
  return __uint_as_float(((unsigned int)h) << 16);
}

// ---------------- preprocessing (unchanged, known-good: 0 bank conflicts) ----------------
// Pre-swizzled rows: within each aligned group of 4x 16B blocks (one BK=32
// K-step), block w goes to w ^ ((row>>1)&3). GEMM stages linearly via
// global_load_lds and applies the same XOR on ds_read (involution).

__global__ __launch_bounds__(256) void binarize_w(const float* __restrict__ W,
                                                  unsigned short* __restrict__ Wb) {
  int gid = blockIdx.x * 256 + threadIdx.x;
  int m  = gid >> 9;
  int b8 = gid & 511;
  const float4* src = (const float4*)(W + ((size_t)m << 12) + (b8 << 3));
  float4 x0 = src[0];
  float4 x1 = src[1];
  float v[8] = {x0.x, x0.y, x0.z, x0.w, x1.x, x1.y, x1.z, x1.w};
  short8 out;
#pragma unroll
  for (int i = 0; i < 8; ++i) {
    float f = v[i];
    out[i] = (short)(unsigned short)(f > 0.f ? 0x3F80u : (f < 0.f ? 0xBF80u : 0u));
  }
  int dstb = (b8 & ~3) | ((b8 & 3) ^ ((m >> 1) & 3));
  *(short8*)(Wb + ((size_t)m << 12) + (dstb << 3)) = out;
}

__global__ __launch_bounds__(256) void split_x(const float* __restrict__ X,
                                               unsigned short* __restrict__ Xhi,
                                               unsigned short* __restrict__ Xlo) {
  int gid = blockIdx.x * 256 + threadIdx.x;
  int m  = gid >> 9;
  int b8 = gid & 511;
  const float4* src = (const float4*)(X + ((size_t)m << 12) + (b8 << 3));
  float4 x0 = src[0];
  float4 x1 = src[1];
  float v[8] = {x0.x, x0.y, x0.z, x0.w, x1.x, x1.y, x1.z, x1.w};
  short8 hi, lo;
#pragma unroll
  for (int i = 0; i < 8; ++i) {
    unsigned short h = f2bf(v[i]);
    hi[i] = (short)h;
    lo[i] = (short)f2bf(v[i] - bf2f(h));
  }
  int dstb = (b8 & ~3) | ((b8 & 3) ^ ((m >> 1) & 3));
  size_t off = ((size_t)m << 12) + (dstb << 3);
  *(short8*)(Xhi + off) = hi;
  *(short8*)(Xlo + off) = lo;
}

// ---------------- GEMM v2: 256x256 tile, BK=32, ring-3 LDS, counted vmcnt ----------------
// 8 waves (2M x 4N), per-wave output 128x64 (8m x 4n fragments).
// Ring-3 slots of {A_hi[256][32], A_lo[256][32], B[256][32]} = 48 KB/slot,
// 144 KB dynamic LDS. Step t: vmcnt(6) + barrier; stage slot[(t+2)%3]
// (6 gll/wave, 2 per phase); 4 phases x 16 MFMA with setprio. Stage target
// = buffer whose reads completed at step t-1 (race-free by the barrier);
// vmcnt(6) keeps 6 loads in flight across the barrier (T4: never drain).

#define GLL(g, l)                                                         \
  __builtin_amdgcn_global_load_lds(                                       \
      (__attribute__((address_space(1))) void*)(g),                       \
      (__attribute__((address_space(3))) void*)(l), 16, 0, 0)

#define SLOT_SHORTS 24576
#define AHI_OFF 0
#define ALO_OFF 8192
#define B_OFF   16384

__global__ __launch_bounds__(512, 2) void gemm_bin2(const unsigned short* __restrict__ Xhi,
                                                    const unsigned short* __restrict__ Xlo,
                                                    const unsigned short* __restrict__ Wb,
                                                    const float* __restrict__ bias,
                                                    float* __restrict__ C) {
  extern __shared__ unsigned short lds[];

  const int NT_N = N_DIM / 256;                // 16
  const int nwg  = (M_DIM / 256) * NT_N;       // 512 (%8==0 -> bijective)
  int bid = blockIdx.x;
  int swz = (bid & 7) * (nwg >> 3) + (bid >> 3);
  int tm = swz / NT_N, tn = swz % NT_N;

  int t = threadIdx.x;
  int lane = t & 63;
  int w = t >> 6;
  int wr = w >> 2;   // 0..1 -> 128-row half
  int wc = w & 3;    // 0..3 -> 64-col quarter

  // staging: thread t covers row (t>>2)+128c, 16B-block t&3, for c=0,1
  int srow = t >> 2, sblk = t & 3;
  const unsigned short* gAh = Xhi + (size_t)(tm * 256 + srow) * K_DIM + sblk * 8;
  const unsigned short* gAl = Xlo + (size_t)(tm * 256 + srow) * K_DIM + sblk * 8;
  const unsigned short* gB  = Wb  + (size_t)(tn * 256 + srow) * K_DIM + sblk * 8;
  const size_t rstep = (size_t)128 * K_DIM;    // +128 rows
  int ld8 = t * 8;                             // per-thread LDS dest (shorts)

  f32x4 acc[8][4];
#pragma unroll
  for (int i = 0; i < 8; ++i)
#pragma unroll
    for (int j = 0; j < 4; ++j) acc[i][j] = (f32x4){0.f, 0.f, 0.f, 0.f};

  // fragment LDS offsets within slot (constant over K-loop); XOR matches prep
  int kb = lane >> 4;
  int laA[8], laB[4];
#pragma unroll
  for (int mi = 0; mi < 8; ++mi) {
    int r = wr * 128 + mi * 16 + (lane & 15);
    laA[mi] = r * 32 + (kb ^ ((r >> 1) & 3)) * 8;
  }
#pragma unroll
  for (int ni = 0; ni < 4; ++ni) {
    int c = wc * 64 + ni * 16 + (lane & 15);
    laB[ni] = c * 32 + (kb ^ ((c >> 1) & 3)) * 8;
  }

  const int nt = K_DIM / 32;   // 128 K-steps (each does hi AND lo vs shared B)

  // prologue: stage steps 0 and 1 (12 gll/wave in flight)
#pragma unroll
  for (int p = 0; p < 2; ++p) {
    unsigned short* ps = lds + p * SLOT_SHORTS;
    int kc = p * 32;
    GLL(gAh + kc,         ps + AHI_OFF + ld8);
    GLL(gAh + kc + rstep, ps + AHI_OFF + 4096 + ld8);
    GLL(gAl + kc,         ps + ALO_OFF + ld8);
    GLL(gAl + kc + rstep, ps + ALO_OFF + 4096 + ld8);
    GLL(gB  + kc,         ps + B_OFF  + ld8);
    GLL(gB  + kc + rstep, ps + B_OFF  + 4096 + ld8);
  }

  int s_cur = 0;
  for (int kt = 0; kt < nt; ++kt) {
    // T4: 6 loads stay in flight across the barrier; step kt's loads landed.
    asm volatile("s_waitcnt vmcnt(6)\n\ts_barrier" ::: "memory");

    int kt2 = kt + 2; if (kt2 > nt - 1) kt2 = nt - 1;   // clamped tail prefetch
    int s_pre = s_cur + 2; if (s_pre >= 3) s_pre -= 3;
    unsigned short* slot  = lds + s_cur * SLOT_SHORTS;
    unsigned short* pslot = lds + s_pre * SLOT_SHORTS;
    int kc = kt2 * 32;

    short8 b[4], ah[4], al[4];
    // ---- phase 0: B + A_hi[0..3] reads, prefetch A_hi, 16 MFMA (hi, m0-3)
#pragma unroll
    for (int ni = 0; ni < 4; ++ni) b[ni] = *(const short8*)&slot[B_OFF + laB[ni]];
#pragma unroll
    for (int mi = 0; mi < 4; ++mi) ah[mi] = *(const short8*)&slot[AHI_OFF + laA[mi]];
    GLL(gAh + kc,         pslot + AHI_OFF + ld8);
    GLL(gAh + kc + rstep, pslot + AHI_OFF + 4096 + ld8);
    __builtin_amdgcn_s_setprio(1);
#pragma unroll
    for (int mi = 0; mi < 4; ++mi)
#pragma unroll
      for (int ni = 0; ni < 4; ++ni)
        acc[mi][ni] = __builtin_amdgcn_mfma_f32_16x16x32_bf16(ah[mi], b[ni], acc[mi][ni], 0, 0, 0);
    __builtin_amdgcn_s_setprio(0);
    // ---- phase 1: A_lo[0..3] reads, prefetch A_lo, 16 MFMA (lo, m0-3)
#pragma unroll
    for (int mi = 0; mi < 4; ++mi) al[mi] = *(const short8*)&slot[ALO_OFF + laA[mi]];
    GLL(gAl + kc,         pslot + ALO_OFF + ld8);
    GLL(gAl + kc + rstep, pslot + ALO_OFF + 4096 + ld8);
    __builtin_amdgcn_s_setprio(1);
#pragma unroll
    for (int mi = 0; mi < 4; ++mi)
#pragma unroll
      for (int ni = 0; ni < 4; ++ni)
        acc[mi][ni] = __builtin_amdgcn_mfma_f32_16x16x32_bf16(al[mi], b[ni], acc[mi][ni], 0, 0, 0);
    __builtin_amdgcn_s_setprio(0);
    // ---- phase 2: A_hi[4..7] reads, prefetch B, 16 MFMA (hi, m4-7)
#pragma unroll
    for (int mi = 0; mi < 4; ++mi) ah[mi] = *(const short8*)&slot[AHI_OFF + laA[mi + 4]];
    GLL(gB + kc,          pslot + B_OFF + ld8);
    GLL(gB + kc + rstep,  pslot + B_OFF + 4096 + ld8);
    __builtin_amdgcn_s_setprio(1);
#pragma unroll
    for (int mi = 0; mi < 4; ++mi)
#pragma unroll
      for (int ni = 0; ni < 4; ++ni)
        acc[mi + 4][ni] = __builtin_amdgcn_mfma_f32_16x16x32_bf16(ah[mi], b[ni], acc[mi + 4][ni], 0, 0, 0);
    __builtin_amdgcn_s_setprio(0);
    // ---- phase 3: A_lo[4..7] reads, 16 MFMA (lo, m4-7)
#pragma unroll
    for (int mi = 0; mi < 4; ++mi) al[mi] = *(const short8*)&slot[ALO_OFF + laA[mi + 4]];
    __builtin_amdgcn_s_setprio(1);
#pragma unroll
    for (int mi = 0; mi < 4; ++mi)
#pragma unroll
      for (int ni = 0; ni < 4; ++ni)
        acc[mi + 4][ni] = __builtin_amdgcn_mfma_f32_16x16x32_bf16(al[mi], b[ni], acc[mi + 4][ni], 0, 0, 0);
    __builtin_amdgcn_s_setprio(0);

    s_cur = (s_cur + 1 == 3) ? 0 : s_cur + 1;
  }

  // epilogue: C/D layout col=lane&15, row=(lane>>4)*4+j  [m89]
  int r0 = tm * 256 + wr * 128;
  int c0 = tn * 256 + wc * 64;
#pragma unroll
  for (int ni = 0; ni < 4; ++ni) {
    int col = c0 + ni * 16 + (lane & 15);
    float bv = bias[col];
#pragma unroll
    for (int mi = 0; mi < 8; ++mi) {
      int row = r0 + mi * 16 + ((lane >> 4) << 2);
#pragma unroll
      for (int j = 0; j < 4; ++j)
        C[(size_t)(row + j) * N_DIM + col] = acc[mi][ni][j] + bv;
    }
  }
}

// ---------------- correct-but-slow fallback (only if ws too small) ----------------
__global__ __launch_bounds__(256) void fallback_gemm(const float* __restrict__ X,
                                                     const float* __restrict__ W,
                                                     const float* __restrict__ bias,
                                                     float* __restrict__ C) {
  int n = blockIdx.x * 16 + (threadIdx.x & 15);
  int m = blockIdx.y * 16 + (threadIdx.x >> 4);
  const float* xr = X + (size_t)m * K_DIM;
  const float* wr = W + (size_t)n * K_DIM;
  float s = 0.f;
  for (int k = 0; k < K_DIM; k += 4) {
    float4 xv = *(const float4*)(xr + k);
    float4 wv = *(const float4*)(wr + k);
    s += xv.x * (wv.x > 0.f ? 1.f : (wv.x < 0.f ? -1.f : 0.f));
    s += xv.y * (wv.y > 0.f ? 1.f : (wv.y < 0.f ? -1.f : 0.f));
    s += xv.z * (wv.z > 0.f ? 1.f : (wv.z < 0.f ? -1.f : 0.f));
    s += xv.w * (wv.w > 0.f ? 1.f : (wv.w < 0.f ? -1.f : 0.f));
  }
  C[(size_t)m * N_DIM + n] = s + bias[n];
}

extern "C" void kernel_launch(void* const* d_in, const int* in_sizes, int n_in,
                              void* d_out, int out_size, void* d_ws, size_t ws_size,
                              hipStream_t stream) {
  const float* X    = (const float*)d_in[0];   // [4,2048,4096] f32
  const float* W    = (const float*)d_in[1];   // [4096,4096] f32
  const float* bias = (const float*)d_in[2];   // [4096] f32
  float* C = (float*)d_out;

  const size_t need = (size_t)N_DIM * K_DIM * 2 + 2 * (size_t)M_DIM * K_DIM * 2;
  if (ws_size >= need) {
    unsigned short* Wb  = (unsigned short*)d_ws;
    unsigned short* Xhi = Wb + (size_t)N_DIM * K_DIM;
    unsigned short* Xlo = Xhi + (size_t)M_DIM * K_DIM;
    binarize_w<<<dim3((N_DIM * K_DIM) / 8 / 256), dim3(256), 0, stream>>>(W, Wb);
    split_x<<<dim3((M_DIM * K_DIM) / 8 / 256), dim3(256), 0, stream>>>(X, Xhi, Xlo);
    static int lds_attr_set = 0;
    if (!lds_attr_set) {   // idempotent attribute set (not a stream op)
      (void)hipFuncSetAttribute((const void*)gemm_bin2,
                                hipFuncAttributeMaxDynamicSharedMemorySize, 147456);
      lds_attr_set = 1;
    }
    gemm_bin2<<<dim3((M_DIM / 256) * (N_DIM / 256)), dim3(512), 147456, stream>>>(Xhi, Xlo, Wb, bias, C);
  } else {
    fallback_gemm<<<dim3(N_DIM / 16, M_DIM / 16), dim3(256), 0, stream>>>(X, W, bias, C);
  }
}

// Round 4
// 474.826 us; speedup vs baseline: 1.8208x; 1.3577x over previous
//
#include <hip/hip_runtime.h>
#include <hip/hip_bf16.h>
#include <stdint.h>

#define M_DIM 8192
#define N_DIM 4096
#define K_DIM 4096

typedef __attribute__((ext_vector_type(8))) short short8;   // 8 bf16 = 4 VGPR
typedef __attribute__((ext_vector_type(4))) float f32x4;

__device__ __forceinline__ unsigned short f2bf(float f) {   // RNE f32->bf16
  unsigned int u = __float_as_uint(f);
  u += 0x7FFFu + ((u >> 16) & 1u);
  return (unsigned short)(u >> 16);
}

// ---------------- preprocessing ----------------
// Pre-swizzled rows: within each aligned group of 4x 16B blocks (one BK=32
// K-step), block w goes to w ^ ((row>>1)&3). GEMM stages linearly via
// global_load_lds and applies the same XOR on ds_read (involution).
// Round-3 PMC: 0 bank conflicts with this scheme.

__global__ __launch_bounds__(256) void binarize_w(const float* __restrict__ W,
                                                  unsigned short* __restrict__ Wb) {
  int gid = blockIdx.x * 256 + threadIdx.x;
  int m  = gid >> 9;
  int b8 = gid & 511;
  const float4* src = (const float4*)(W + ((size_t)m << 12) + (b8 << 3));
  float4 x0 = src[0];
  float4 x1 = src[1];
  float v[8] = {x0.x, x0.y, x0.z, x0.w, x1.x, x1.y, x1.z, x1.w};
  short8 out;
#pragma unroll
  for (int i = 0; i < 8; ++i) {
    float f = v[i];
    out[i] = (short)(unsigned short)(f > 0.f ? 0x3F80u : (f < 0.f ? 0xBF80u : 0u));
  }
  int dstb = (b8 & ~3) | ((b8 & 3) ^ ((m >> 1) & 3));
  *(short8*)(Wb + ((size_t)m << 12) + (dstb << 3)) = out;
}

// single-plane bf16 conversion of X (RNE); error bound ~0.4 absmax at output
__global__ __launch_bounds__(256) void cvt_x(const float* __restrict__ X,
                                             unsigned short* __restrict__ Xb) {
  int gid = blockIdx.x * 256 + threadIdx.x;
  int m  = gid >> 9;
  int b8 = gid & 511;
  const float4* src = (const float4*)(X + ((size_t)m << 12) + (b8 << 3));
  float4 x0 = src[0];
  float4 x1 = src[1];
  float v[8] = {x0.x, x0.y, x0.z, x0.w, x1.x, x1.y, x1.z, x1.w};
  short8 out;
#pragma unroll
  for (int i = 0; i < 8; ++i) out[i] = (short)f2bf(v[i]);
  int dstb = (b8 & ~3) | ((b8 & 3) ^ ((m >> 1) & 3));
  *(short8*)(Xb + ((size_t)m << 12) + (dstb << 3)) = out;
}

// ---------------- GEMM v3: single bf16 plane, 256x256 tile, BK=32, ring-3 ----------------
// 8 waves (2M x 4N), per-wave output 128x64 (8m x 4n 16x16 fragments).
// Ring-3 slots of {A[256][32], B[256][32]} = 32 KB/slot, 96 KB dynamic LDS.
// Step t: vmcnt(4)+barrier; 2 phases x {ds_read, 2x GLL into slot t+2,
// setprio(1), 16 MFMA}. Counted vmcnt (T4): 4 loads stay in flight across
// the barrier. Race-free per round-3 analysis (prefetch distance 2, ring 3).

#define GLL(g, l)                                                         \
  __builtin_amdgcn_global_load_lds(                                       \
      (__attribute__((address_space(1))) void*)(g),                       \
      (__attribute__((address_space(3))) void*)(l), 16, 0, 0)

#define SLOT_SHORTS 16384
#define B_OFF       8192

__global__ __launch_bounds__(512, 2) void gemm_bin3(const unsigned short* __restrict__ Xb,
                                                    const unsigned short* __restrict__ Wb,
                                                    const float* __restrict__ bias,
                                                    float* __restrict__ C) {
  extern __shared__ unsigned short lds[];

  const int NT_N = N_DIM / 256;                // 16
  const int nwg  = (M_DIM / 256) * NT_N;       // 512 (%8==0 -> bijective)
  int bid = blockIdx.x;
  int swz = (bid & 7) * (nwg >> 3) + (bid >> 3);
  int tm = swz / NT_N, tn = swz % NT_N;

  int t = threadIdx.x;
  int lane = t & 63;
  int w = t >> 6;
  int wr = w >> 2;   // 0..1 -> 128-row half
  int wc = w & 3;    // 0..3 -> 64-col quarter

  int srow = t >> 2, sblk = t & 3;
  const unsigned short* gA = Xb + (size_t)(tm * 256 + srow) * K_DIM + sblk * 8;
  const unsigned short* gB = Wb + (size_t)(tn * 256 + srow) * K_DIM + sblk * 8;
  const size_t rstep = (size_t)128 * K_DIM;
  int ld8 = t * 8;

  f32x4 acc[8][4];
#pragma unroll
  for (int i = 0; i < 8; ++i)
#pragma unroll
    for (int j = 0; j < 4; ++j) acc[i][j] = (f32x4){0.f, 0.f, 0.f, 0.f};

  int kb = lane >> 4;
  int laA[8], laB[4];
#pragma unroll
  for (int mi = 0; mi < 8; ++mi) {
    int r = wr * 128 + mi * 16 + (lane & 15);
    laA[mi] = r * 32 + (kb ^ ((r >> 1) & 3)) * 8;
  }
#pragma unroll
  for (int ni = 0; ni < 4; ++ni) {
    int c = wc * 64 + ni * 16 + (lane & 15);
    laB[ni] = c * 32 + (kb ^ ((c >> 1) & 3)) * 8;
  }

  const int nt = K_DIM / 32;   // 128 K-steps

  // prologue: stage steps 0 and 1 (8 loads/wave in flight)
#pragma unroll
  for (int p = 0; p < 2; ++p) {
    unsigned short* ps = lds + p * SLOT_SHORTS;
    int kc = p * 32;
    GLL(gA + kc,         ps + ld8);
    GLL(gA + kc + rstep, ps + 4096 + ld8);
    GLL(gB + kc,         ps + B_OFF + ld8);
    GLL(gB + kc + rstep, ps + B_OFF + 4096 + ld8);
  }

  int s_cur = 0;
  for (int kt = 0; kt < nt; ++kt) {
    // T4: this wave's step-kt loads done; 4 (step kt+1) stay in flight.
    asm volatile("s_waitcnt vmcnt(4)\n\ts_barrier" ::: "memory");

    int kt2 = kt + 2; if (kt2 > nt - 1) kt2 = nt - 1;   // clamped tail prefetch
    int s_pre = s_cur + 2; if (s_pre >= 3) s_pre -= 3;
    unsigned short* slot  = lds + s_cur * SLOT_SHORTS;
    unsigned short* pslot = lds + s_pre * SLOT_SHORTS;
    int kc = kt2 * 32;

    short8 b[4], a[4];
    // ---- phase 0: B[0..3] + A[0..3] reads, prefetch A, 16 MFMA (m0-3)
#pragma unroll
    for (int ni = 0; ni < 4; ++ni) b[ni] = *(const short8*)&slot[B_OFF + laB[ni]];
#pragma unroll
    for (int mi = 0; mi < 4; ++mi) a[mi] = *(const short8*)&slot[laA[mi]];
    GLL(gA + kc,         pslot + ld8);
    GLL(gA + kc + rstep, pslot + 4096 + ld8);
    __builtin_amdgcn_s_setprio(1);
#pragma unroll
    for (int mi = 0; mi < 4; ++mi)
#pragma unroll
      for (int ni = 0; ni < 4; ++ni)
        acc[mi][ni] = __builtin_amdgcn_mfma_f32_16x16x32_bf16(a[mi], b[ni], acc[mi][ni], 0, 0, 0);
    __builtin_amdgcn_s_setprio(0);
    // ---- phase 1: A[4..7] reads, prefetch B, 16 MFMA (m4-7)
#pragma unroll
    for (int mi = 0; mi < 4; ++mi) a[mi] = *(const short8*)&slot[laA[mi + 4]];
    GLL(gB + kc,         pslot + B_OFF + ld8);
    GLL(gB + kc + rstep, pslot + B_OFF + 4096 + ld8);
    __builtin_amdgcn_s_setprio(1);
#pragma unroll
    for (int mi = 0; mi < 4; ++mi)
#pragma unroll
      for (int ni = 0; ni < 4; ++ni)
        acc[mi + 4][ni] = __builtin_amdgcn_mfma_f32_16x16x32_bf16(a[mi], b[ni], acc[mi + 4][ni], 0, 0, 0);
    __builtin_amdgcn_s_setprio(0);

    s_cur = (s_cur + 1 == 3) ? 0 : s_cur + 1;
  }

  // epilogue: C/D layout col=lane&15, row=(lane>>4)*4+j  [m89]
  int r0 = tm * 256 + wr * 128;
  int c0 = tn * 256 + wc * 64;
#pragma unroll
  for (int ni = 0; ni < 4; ++ni) {
    int col = c0 + ni * 16 + (lane & 15);
    float bv = bias[col];
#pragma unroll
    for (int mi = 0; mi < 8; ++mi) {
      int row = r0 + mi * 16 + ((lane >> 4) << 2);
#pragma unroll
      for (int j = 0; j < 4; ++j)
        C[(size_t)(row + j) * N_DIM + col] = acc[mi][ni][j] + bv;
    }
  }
}

// ---------------- correct-but-slow fallback (only if ws too small) ----------------
__global__ __launch_bounds__(256) void fallback_gemm(const float* __restrict__ X,
                                                     const float* __restrict__ W,
                                                     const float* __restrict__ bias,
                                                     float* __restrict__ C) {
  int n = blockIdx.x * 16 + (threadIdx.x & 15);
  int m = blockIdx.y * 16 + (threadIdx.x >> 4);
  const float* xr = X + (size_t)m * K_DIM;
  const float* wr = W + (size_t)n * K_DIM;
  float s = 0.f;
  for (int k = 0; k < K_DIM; k += 4) {
    float4 xv = *(const float4*)(xr + k);
    float4 wv = *(const float4*)(wr + k);
    s += xv.x * (wv.x > 0.f ? 1.f : (wv.x < 0.f ? -1.f : 0.f));
    s += xv.y * (wv.y > 0.f ? 1.f : (wv.y < 0.f ? -1.f : 0.f));
    s += xv.z * (wv.z > 0.f ? 1.f : (wv.z < 0.f ? -1.f : 0.f));
    s += xv.w * (wv.w > 0.f ? 1.f : (wv.w < 0.f ? -1.f : 0.f));
  }
  C[(size_t)m * N_DIM + n] = s + bias[n];
}

extern "C" void kernel_launch(void* const* d_in, const int* in_sizes, int n_in,
                              void* d_out, int out_size, void* d_ws, size_t ws_size,
                              hipStream_t stream) {
  const float* X    = (const float*)d_in[0];   // [4,2048,4096] f32
  const float* W    = (const float*)d_in[1];   // [4096,4096] f32
  const float* bias = (const float*)d_in[2];   // [4096] f32
  float* C = (float*)d_out;

  const size_t need = (size_t)N_DIM * K_DIM * 2      // Wb (32 MB)
                    + (size_t)M_DIM * K_DIM * 2;     // Xb (64 MB)
  if (ws_size >= need) {
    unsigned short* Wb = (unsigned short*)d_ws;
    unsigned short* Xb = Wb + (size_t)N_DIM * K_DIM;
    binarize_w<<<dim3((N_DIM * K_DIM) / 8 / 256), dim3(256), 0, stream>>>(W, Wb);
    cvt_x<<<dim3((M_DIM * K_DIM) / 8 / 256), dim3(256), 0, stream>>>(X, Xb);
    static int lds_attr_set = 0;
    if (!lds_attr_set) {   // idempotent attribute set (not a stream op)
      (void)hipFuncSetAttribute((const void*)gemm_bin3,
                                hipFuncAttributeMaxDynamicSharedMemorySize, 98304);
      lds_attr_set = 1;
    }
    gemm_bin3<<<dim3((M_DIM / 256) * (N_DIM / 256)), dim3(512), 98304, stream>>>(Xb, Wb, bias, C);
  } else {
    fallback_gemm<<<dim3(N_DIM / 16, M_DIM / 16), dim3(256), 0, stream>>>(X, W, bias, C);
  }
}